// Round 3
// baseline (162.846 us; speedup 1.0000x reference)
//
#include <hip/hip_runtime.h>
#include <hip/hip_bf16.h>
#include <stdint.h>

#define T_SEQ 4096
#define CDIM  1024
#define NH    16
#define DHEAD 64
#define BAND  128

typedef __bf16 bf16;
typedef __attribute__((ext_vector_type(8))) __bf16 bf16x8;
typedef __attribute__((ext_vector_type(4))) __bf16 bf16x4;
typedef __attribute__((ext_vector_type(4))) float  f32x4;

// 0.125 (1/sqrt(64)) * log2(e): folded into Q so attn softmax is pure exp2
#define QSCALE 0.1803368801111204f

__device__ __forceinline__ void async_ld16(const bf16* g, bf16* l) {
    __builtin_amdgcn_global_load_lds(
        (__attribute__((address_space(1))) void*)g,
        (__attribute__((address_space(3))) void*)l, 16, 0, 0);
}

// ---------------------------------------------------------------------------
// fp32 -> bf16, 8 elems/thread: x (4194304) + [Wq;Wk;Wv] (3145728)
// (Wo is converted inside attn's prologue)
// ---------------------------------------------------------------------------
__global__ void cvt_all(const float* __restrict__ x,  const float* __restrict__ wq,
                        const float* __restrict__ wk, const float* __restrict__ wv,
                        bf16* __restrict__ xb, bf16* __restrict__ wqkvb) {
    size_t g = (size_t)blockIdx.x * 256 + threadIdx.x;   // group of 8 elems
    const float* s; bf16* d;
    if (g < 524288) {                       // x
        s = x + g * 8; d = xb + g * 8;
    } else {                                // Wq/Wk/Wv -> wqkvb
        size_t i2 = (g - 524288) * 8;
        int which = (int)(i2 >> 20);
        s = ((which == 0) ? wq : (which == 1) ? wk : wv) + (i2 & 1048575);
        d = wqkvb + i2;
    }
    const float4* sv = (const float4*)s;
    float4 a = sv[0], b = sv[1];
    bf16x8 o;
    o[0] = (bf16)a.x; o[1] = (bf16)a.y; o[2] = (bf16)a.z; o[3] = (bf16)a.w;
    o[4] = (bf16)b.x; o[5] = (bf16)b.y; o[6] = (bf16)b.z; o[7] = (bf16)b.w;
    *(bf16x8*)d = o;
}

// ---------------------------------------------------------------------------
// QKV GEMM: C[m,n] = sum_k A[m,k]*B[n,k]   A=4096x1024 (x), B=3072x1024 (Wqkv)
// 128x128 tile, BK=32, 4 waves (2x2 of 64x64), 16x16x32 bf16 MFMA.
// Per-block n-range is uniformly Q, K, or V:
//   Q (bn<8):  store (H,T,64), scaled by QSCALE
//   K (bn<16): store (H,T,64)
//   V (bn>=16): store V^T (H,64,T) via LDS transpose -> coalesced dwordx4
// ---------------------------------------------------------------------------
__global__ __launch_bounds__(256) void gemm_qkv(
        const bf16* __restrict__ A, const bf16* __restrict__ B,
        bf16* __restrict__ qb, bf16* __restrict__ kb, bf16* __restrict__ vtb) {
    const int K = 1024;
    __shared__ __align__(16) bf16 smem[8192];      // lds_a(4096) + lds_b(4096)
    bf16* lds_a = smem;
    bf16* lds_b = smem + 4096;
    int t = threadIdx.x;
    int w = t >> 6, l = t & 63;
    int quad = l >> 4, col = l & 15;
    int bx = blockIdx.x;
    int bm = bx & 31, bn = bx >> 5;          // 32 x 24 blocks
    int m0 = bm * 128, n0 = bn * 128;
    int wm = (w >> 1) * 64, wn = (w & 1) * 64;

    f32x4 acc[4][4];
#pragma unroll
    for (int i = 0; i < 4; i++)
#pragma unroll
        for (int j = 0; j < 4; j++) acc[i][j] = (f32x4){0.f, 0.f, 0.f, 0.f};

    int c0 = t, c1 = 256 + t;
    int ra0 = c0 >> 2, ka0 = (c0 & 3) * 8;
    int ra1 = c1 >> 2, ka1 = (c1 & 3) * 8;
    bf16* la0 = lds_a + (size_t)(w * 64) * 8;
    bf16* la1 = lds_a + (size_t)(256 + w * 64) * 8;
    bf16* lb0 = lds_b + (size_t)(w * 64) * 8;
    bf16* lb1 = lds_b + (size_t)(256 + w * 64) * 8;

    for (int k0 = 0; k0 < K; k0 += 32) {
        async_ld16(A + (size_t)(m0 + ra0) * K + k0 + ka0, la0);
        async_ld16(A + (size_t)(m0 + ra1) * K + k0 + ka1, la1);
        async_ld16(B + (size_t)(n0 + ra0) * K + k0 + ka0, lb0);
        async_ld16(B + (size_t)(n0 + ra1) * K + k0 + ka1, lb1);
        __syncthreads();
        const bf16x8* pa = (const bf16x8*)lds_a;
        const bf16x8* pb = (const bf16x8*)lds_b;
        bf16x8 af[4], bfr[4];
#pragma unroll
        for (int i = 0; i < 4; i++) af[i]  = pa[(wm + i * 16 + col) * 4 + quad];
#pragma unroll
        for (int j = 0; j < 4; j++) bfr[j] = pb[(wn + j * 16 + col) * 4 + quad];
#pragma unroll
        for (int i = 0; i < 4; i++)
#pragma unroll
            for (int j = 0; j < 4; j++)
                acc[i][j] = __builtin_amdgcn_mfma_f32_16x16x32_bf16(af[i], bfr[j], acc[i][j], 0, 0, 0);
        __syncthreads();
    }

    if (n0 < 2048) {
        // Q or K: (H,T,64) row layout
        bool isQ = (n0 < 1024);
        bf16* dst = isQ ? qb : kb;
        float scale = isQ ? QSCALE : 1.0f;
        int obase = n0 & 1023;
#pragma unroll
        for (int i = 0; i < 4; i++)
#pragma unroll
            for (int j = 0; j < 4; j++) {
                int mbase = m0 + wm + i * 16 + quad * 4;
                int o = obase + wn + j * 16 + col;
                int h = o >> 6, d = o & 63;
#pragma unroll
                for (int r = 0; r < 4; r++)
                    dst[((size_t)(h * T_SEQ + mbase + r)) * 64 + d] =
                        (bf16)(acc[i][j][r] * scale);
            }
    } else {
        // V: transpose 128n x 128m through LDS in 4 chunks of 32n
        int obase = n0 - 2048;
        bf16* tb = smem;                      // 32*136 = 4352 elems (8704 B)
#pragma unroll
        for (int c = 0; c < 4; c++) {
            __syncthreads();                  // previous chunk fully read
            if ((w & 1) == (c >> 1)) {
                int jlo = 2 * (c & 1);
#pragma unroll
                for (int i = 0; i < 4; i++)
#pragma unroll
                    for (int jj = 0; jj < 2; jj++) {
                        int j = jlo + jj;
                        int nl = jj * 16 + col;
                        int mb = wm + i * 16 + quad * 4;
                        bf16x4 pk;
#pragma unroll
                        for (int r = 0; r < 4; r++) pk[r] = (bf16)acc[i][j][r];
                        *(bf16x4*)(tb + nl * 136 + mb) = pk;
                    }
            }
            __syncthreads();
#pragma unroll
            for (int rd = 0; rd < 2; rd++) {
                int nrow = rd * 16 + w * 4 + (l >> 4);
                int moff = (l & 15) * 8;
                bf16x8 vrow = *(const bf16x8*)(tb + nrow * 136 + moff);
                *(bf16x8*)(vtb + (size_t)(obase + c * 32 + nrow) * T_SEQ + m0 + moff) = vrow;
            }
        }
    }
}

// ---------------------------------------------------------------------------
// Banded attention, single-pass: block = (head, 64 q-rows) = 2 waves,
// wave owns 32 rows; key window [rowbase-128, rowbase+32) = 10 x 16 tiles.
// Q pre-scaled by 0.125*log2e -> softmax is pure exp2.
// Prologue: converts Wo fp32->bf16 (exactly 1 group of 8 per thread).
// ---------------------------------------------------------------------------
#define PSTR 168

__global__ __launch_bounds__(128) void attn(
        const bf16* __restrict__ qbuf, const bf16* __restrict__ kbuf,
        const bf16* __restrict__ vtbuf, bf16* __restrict__ yb,
        const float* __restrict__ wo, bf16* __restrict__ wob) {
    __shared__ __align__(16) bf16 p_lds[2 * 32 * PSTR];
    int t = threadIdx.x;
    int w = t >> 6, l = t & 63;
    int quad = l >> 4, col = l & 15;

    // Wo conversion: 1024 blocks * 128 threads * 8 elems = 1048576 exactly
    {
        size_t g = ((size_t)blockIdx.x * 128 + t) * 8;
        const float4* sv = (const float4*)(wo + g);
        float4 a = sv[0], b = sv[1];
        bf16x8 o8;
        o8[0] = (bf16)a.x; o8[1] = (bf16)a.y; o8[2] = (bf16)a.z; o8[3] = (bf16)a.w;
        o8[4] = (bf16)b.x; o8[5] = (bf16)b.y; o8[6] = (bf16)b.z; o8[7] = (bf16)b.w;
        *(bf16x8*)(wob + g) = o8;
    }

    int h = blockIdx.x >> 6;       // 16 heads
    int qt = blockIdx.x & 63;      // 64 q-tiles of 64 rows
    int i0 = qt * 64;
    int rowbase = i0 + w * 32;
    int jbase = rowbase - 128;

    const bf16* Q  = qbuf  + (size_t)h * T_SEQ * 64;
    const bf16* Kp = kbuf  + (size_t)h * T_SEQ * 64;
    const bf16* Vt = vtbuf + (size_t)h * 64 * T_SEQ;

    bf16x8 qf[2][2];
#pragma unroll
    for (int mi = 0; mi < 2; mi++)
#pragma unroll
        for (int kk = 0; kk < 2; kk++)
            qf[mi][kk] = *(const bf16x8*)(Q + (size_t)(rowbase + mi * 16 + col) * 64 + kk * 32 + quad * 8);

    f32x4 s[2][10];
#pragma unroll
    for (int mi = 0; mi < 2; mi++)
#pragma unroll
        for (int nj = 0; nj < 10; nj++) s[mi][nj] = (f32x4){0.f, 0.f, 0.f, 0.f};
#pragma unroll
    for (int nj = 0; nj < 10; nj++) {
        int jr = jbase + nj * 16 + col;
        int jl = jr < 0 ? 0 : jr;
#pragma unroll
        for (int kk = 0; kk < 2; kk++) {
            bf16x8 kf = *(const bf16x8*)(Kp + (size_t)jl * 64 + kk * 32 + quad * 8);
#pragma unroll
            for (int mi = 0; mi < 2; mi++)
                s[mi][nj] = __builtin_amdgcn_mfma_f32_16x16x32_bf16(qf[mi][kk], kf, s[mi][nj], 0, 0, 0);
        }
    }

    // mask + softmax in base 2 (scores already carry 0.125*log2e)
    float l_run[2][4];
#pragma unroll
    for (int mi = 0; mi < 2; mi++)
#pragma unroll
        for (int r = 0; r < 4; r++) {
            int ii = rowbase + mi * 16 + quad * 4 + r;
            float mx = -3.0e38f;
#pragma unroll
            for (int nj = 0; nj < 10; nj++) {
                int jj = jbase + nj * 16 + col;
                bool ok = (jj >= 0) && ((unsigned)(ii - jj) < (unsigned)BAND);
                float v = ok ? s[mi][nj][r] : -3.0e38f;
                s[mi][nj][r] = v;
                mx = fmaxf(mx, v);
            }
            mx = fmaxf(mx, __shfl_xor(mx, 1));
            mx = fmaxf(mx, __shfl_xor(mx, 2));
            mx = fmaxf(mx, __shfl_xor(mx, 4));
            mx = fmaxf(mx, __shfl_xor(mx, 8));
            float rs = 0.f;
#pragma unroll
            for (int nj = 0; nj < 10; nj++) {
                float p = __builtin_amdgcn_exp2f(s[mi][nj][r] - mx);
                s[mi][nj][r] = p;
                rs += p;
            }
            rs += __shfl_xor(rs, 1);
            rs += __shfl_xor(rs, 2);
            rs += __shfl_xor(rs, 4);
            rs += __shfl_xor(rs, 8);
            l_run[mi][r] = rs;
        }

    bf16* myp = p_lds + (size_t)w * (32 * PSTR);
#pragma unroll
    for (int mi = 0; mi < 2; mi++)
#pragma unroll
        for (int nj = 0; nj < 10; nj++)
#pragma unroll
            for (int r = 0; r < 4; r++)
                myp[(mi * 16 + quad * 4 + r) * PSTR + nj * 16 + col] = (bf16)s[mi][nj][r];

    f32x4 o_acc[2][4];
#pragma unroll
    for (int mi = 0; mi < 2; mi++)
#pragma unroll
        for (int di = 0; di < 4; di++) o_acc[mi][di] = (f32x4){0.f, 0.f, 0.f, 0.f};
#pragma unroll
    for (int kj = 0; kj < 5; kj++) {
        int jv = jbase + kj * 32 + quad * 8;
        int jvc = jv < 0 ? 0 : jv;
        bf16x8 pf[2];
#pragma unroll
        for (int mi = 0; mi < 2; mi++)
            pf[mi] = *(const bf16x8*)(myp + (mi * 16 + col) * PSTR + kj * 32 + quad * 8);
#pragma unroll
        for (int di = 0; di < 4; di++) {
            bf16x8 vf = *(const bf16x8*)(Vt + (size_t)(di * 16 + col) * T_SEQ + jvc);
#pragma unroll
            for (int mi = 0; mi < 2; mi++)
                o_acc[mi][di] = __builtin_amdgcn_mfma_f32_16x16x32_bf16(pf[mi], vf, o_acc[mi][di], 0, 0, 0);
        }
    }

#pragma unroll
    for (int mi = 0; mi < 2; mi++)
#pragma unroll
        for (int di = 0; di < 4; di++)
#pragma unroll
            for (int r = 0; r < 4; r++) {
                int tt = rowbase + mi * 16 + quad * 4 + r;
                int c = h * 64 + di * 16 + col;
                yb[(size_t)tt * CDIM + c] = (bf16)(o_acc[mi][di][r] / l_run[mi][r]);
            }
}

// ---------------------------------------------------------------------------
// Output projection: out[t,o] = sum_c y[t,c]*Wo[o,c], fp32 out.
// 64x128 tile -> 512 blocks (2 blocks/CU). 4 waves as 2x2 of 32x64.
// ---------------------------------------------------------------------------
__global__ __launch_bounds__(256) void gemm_proj(
        const bf16* __restrict__ A, const bf16* __restrict__ B,
        float* __restrict__ Cout) {
    const int K = 1024;
    __shared__ __align__(16) bf16 lds_a[64 * 32];
    __shared__ __align__(16) bf16 lds_b[128 * 32];
    int t = threadIdx.x;
    int w = t >> 6, l = t & 63;
    int quad = l >> 4, col = l & 15;
    int bx = blockIdx.x;
    int bm = bx & 63, bn = bx >> 6;          // 64 x 8 blocks
    int m0 = bm * 64, n0 = bn * 128;
    int wm = (w >> 1) * 32, wn = (w & 1) * 64;

    f32x4 acc[2][4];
#pragma unroll
    for (int i = 0; i < 2; i++)
#pragma unroll
        for (int j = 0; j < 4; j++) acc[i][j] = (f32x4){0.f, 0.f, 0.f, 0.f};

    int ra0 = t >> 2, ka0 = (t & 3) * 8;
    int c1 = t, c2 = 256 + t;
    int rb1 = c1 >> 2, kb1 = (c1 & 3) * 8;
    int rb2 = c2 >> 2, kb2 = (c2 & 3) * 8;
    bf16* la0 = lds_a + (size_t)(w * 64) * 8;
    bf16* lb1 = lds_b + (size_t)(w * 64) * 8;
    bf16* lb2 = lds_b + (size_t)(256 + w * 64) * 8;

    for (int k0 = 0; k0 < K; k0 += 32) {
        async_ld16(A + (size_t)(m0 + ra0) * K + k0 + ka0, la0);
        async_ld16(B + (size_t)(n0 + rb1) * K + k0 + kb1, lb1);
        async_ld16(B + (size_t)(n0 + rb2) * K + k0 + kb2, lb2);
        __syncthreads();
        const bf16x8* pa = (const bf16x8*)lds_a;
        const bf16x8* pb = (const bf16x8*)lds_b;
        bf16x8 af[2], bfr[4];
#pragma unroll
        for (int i = 0; i < 2; i++) af[i]  = pa[(wm + i * 16 + col) * 4 + quad];
#pragma unroll
        for (int j = 0; j < 4; j++) bfr[j] = pb[(wn + j * 16 + col) * 4 + quad];
#pragma unroll
        for (int i = 0; i < 2; i++)
#pragma unroll
            for (int j = 0; j < 4; j++)
                acc[i][j] = __builtin_amdgcn_mfma_f32_16x16x32_bf16(af[i], bfr[j], acc[i][j], 0, 0, 0);
        __syncthreads();
    }
#pragma unroll
    for (int i = 0; i < 2; i++)
#pragma unroll
        for (int j = 0; j < 4; j++) {
            int mbase = m0 + wm + i * 16 + quad * 4;
            int ncol = n0 + wn + j * 16 + col;
#pragma unroll
            for (int r = 0; r < 4; r++)
                Cout[(size_t)(mbase + r) * CDIM + ncol] = acc[i][j][r];
        }
}

extern "C" void kernel_launch(void* const* d_in, const int* in_sizes, int n_in,
                              void* d_out, int out_size, void* d_ws, size_t ws_size,
                              hipStream_t stream) {
    const float* x  = (const float*)d_in[0];
    const float* Wq = (const float*)d_in[1];
    const float* Wk = (const float*)d_in[2];
    const float* Wv = (const float*)d_in[3];
    const float* Wo = (const float*)d_in[4];
    float* out = (float*)d_out;

    char* ws = (char*)d_ws;
    bf16* xb    = (bf16*)(ws);                        //  8 MB  x bf16
    bf16* wqkvb = (bf16*)(ws + ((size_t)8  << 20));   //  6 MB  [Wq;Wk;Wv]
    bf16* wob   = (bf16*)(ws + ((size_t)14 << 20));   //  2 MB  Wo
    bf16* qb    = (bf16*)(ws + ((size_t)16 << 20));   //  8 MB  Q (H,T,64), pre-scaled
    bf16* kb    = (bf16*)(ws + ((size_t)24 << 20));   //  8 MB  K (H,T,64)
    bf16* vtb   = (bf16*)(ws + ((size_t)32 << 20));   //  8 MB  V^T (H,64,T)
    bf16* yb    = (bf16*)(ws + ((size_t)40 << 20));   //  8 MB  y (T,C)

    cvt_all<<<3584, 256, 0, stream>>>(x, Wq, Wk, Wv, xb, wqkvb);
    gemm_qkv<<<768, 256, 0, stream>>>(xb, wqkvb, qb, kb, vtb);
    attn<<<1024, 128, 0, stream>>>(qb, kb, vtb, yb, Wo, wob);
    gemm_proj<<<512, 256, 0, stream>>>(yb, wob, out);
}

// Round 4
// 148.460 us; speedup vs baseline: 1.0969x; 1.0969x over previous
//
#include <hip/hip_runtime.h>
#include <hip/hip_bf16.h>
#include <stdint.h>

#define T_SEQ 4096
#define CDIM  1024
#define NH    16
#define DHEAD 64
#define BAND  128

typedef __bf16 bf16;
typedef __attribute__((ext_vector_type(8)))  __bf16 bf16x8;
typedef __attribute__((ext_vector_type(4)))  __bf16 bf16x4;
typedef __attribute__((ext_vector_type(4)))  float  f32x4;
typedef __attribute__((ext_vector_type(16))) float  f32x16;

// 0.125 (1/sqrt(64)) * log2(e): folded into Q so attn softmax is pure exp2
#define QSCALE 0.1803368801111204f

// XOR swizzle of the 4 16B k-chunk slots per 32-elem LDS row: makes the
// 32x32x16 A/B fragment b128 reads bank-conflict-free (each 8-lane phase
// covers all 32 banks exactly once).
#define SWZ(r) (((r) ^ ((r) >> 2)) & 3)

__device__ __forceinline__ void async_ld16(const bf16* g, bf16* l) {
    __builtin_amdgcn_global_load_lds(
        (__attribute__((address_space(1))) void*)g,
        (__attribute__((address_space(3))) void*)l, 16, 0, 0);
}

// ---------------------------------------------------------------------------
// fp32 -> bf16, 8 elems/thread: x (4194304) + [Wq;Wk;Wv] (3145728)
// (Wo is converted inside attn's prologue)
// ---------------------------------------------------------------------------
__global__ void cvt_all(const float* __restrict__ x,  const float* __restrict__ wq,
                        const float* __restrict__ wk, const float* __restrict__ wv,
                        bf16* __restrict__ xb, bf16* __restrict__ wqkvb) {
    size_t g = (size_t)blockIdx.x * 256 + threadIdx.x;
    const float* s; bf16* d;
    if (g < 524288) {
        s = x + g * 8; d = xb + g * 8;
    } else {
        size_t i2 = (g - 524288) * 8;
        int which = (int)(i2 >> 20);
        s = ((which == 0) ? wq : (which == 1) ? wk : wv) + (i2 & 1048575);
        d = wqkvb + i2;
    }
    const float4* sv = (const float4*)s;
    float4 a = sv[0], b = sv[1];
    bf16x8 o;
    o[0] = (bf16)a.x; o[1] = (bf16)a.y; o[2] = (bf16)a.z; o[3] = (bf16)a.w;
    o[4] = (bf16)b.x; o[5] = (bf16)b.y; o[6] = (bf16)b.z; o[7] = (bf16)b.w;
    *(bf16x8*)d = o;
}

// ---------------------------------------------------------------------------
// QKV GEMM: C[m,n] = sum_k A[m,k]*B[n,k]   A=4096x1024 (x), B=3072x1024
// 128x128 tile, BK=32, 4 waves (2x2 of 64x64), 32x32x16 bf16 MFMA,
// swizzled LDS (conflict-free b128 frag reads).
//   Q (n<1024):  (H,T,64), scaled by QSCALE   K (n<2048): (H,T,64)
//   V (n>=2048): V^T (H*64, T) via packed bf16x4 register-quad stores
// ---------------------------------------------------------------------------
__global__ __launch_bounds__(256) void gemm_qkv(
        const bf16* __restrict__ A, const bf16* __restrict__ B,
        bf16* __restrict__ qb, bf16* __restrict__ kb, bf16* __restrict__ vtb) {
    const int K = 1024;
    __shared__ __align__(16) bf16 lds_a[128 * 32];
    __shared__ __align__(16) bf16 lds_b[128 * 32];
    int t = threadIdx.x;
    int w = t >> 6, l = t & 63;
    int e31 = l & 31, h2 = l >> 5;
    int bx = blockIdx.x;
    int bm = bx & 31, bn = bx >> 5;          // 32 x 24 blocks
    int m0 = bm * 128, n0 = bn * 128;
    int wm = (w >> 1) * 64, wn = (w & 1) * 64;

    f32x16 acc[2][2];
#pragma unroll
    for (int i = 0; i < 2; i++)
#pragma unroll
        for (int j = 0; j < 2; j++)
#pragma unroll
            for (int r = 0; r < 16; r++) acc[i][j][r] = 0.f;

    // staging: chunk c -> LDS row c>>2, phys slot c&3; fetch logical k-chunk
    // (c&3)^SWZ(row) so that phys slot p holds logical p^SWZ(row)
    int c0 = t, c1 = 256 + t;
    int ra0 = c0 >> 2, ra1 = c1 >> 2;
    int ka0 = ((c0 & 3) ^ SWZ(ra0)) * 8;
    int ka1 = ((c1 & 3) ^ SWZ(ra1)) * 8;
    bf16* la0 = lds_a + w * 512;
    bf16* la1 = lds_a + 2048 + w * 512;
    bf16* lb0 = lds_b + w * 512;
    bf16* lb1 = lds_b + 2048 + w * 512;

    // K-invariant fragment pointers (A-layout: m=lane&31, k=8*(lane>>5)+j)
    const bf16x8* pa[2][2];
    const bf16x8* pb[2][2];
#pragma unroll
    for (int i = 0; i < 2; i++) {
        int rowa = wm + i * 32 + e31;
        int rowb = wn + i * 32 + e31;
        int sa = SWZ(rowa), sb = SWZ(rowb);
#pragma unroll
        for (int kc = 0; kc < 2; kc++) {
            pa[i][kc] = (const bf16x8*)(lds_a + rowa * 32 + ((kc * 2 + h2) ^ sa) * 8);
            pb[i][kc] = (const bf16x8*)(lds_b + rowb * 32 + ((kc * 2 + h2) ^ sb) * 8);
        }
    }

    for (int k0 = 0; k0 < K; k0 += 32) {
        async_ld16(A + (size_t)(m0 + ra0) * K + k0 + ka0, la0);
        async_ld16(A + (size_t)(m0 + ra1) * K + k0 + ka1, la1);
        async_ld16(B + (size_t)(n0 + ra0) * K + k0 + ka0, lb0);
        async_ld16(B + (size_t)(n0 + ra1) * K + k0 + ka1, lb1);
        __syncthreads();
        bf16x8 af[2][2], bv[2][2];
#pragma unroll
        for (int i = 0; i < 2; i++)
#pragma unroll
            for (int kc = 0; kc < 2; kc++) { af[i][kc] = *pa[i][kc]; bv[i][kc] = *pb[i][kc]; }
#pragma unroll
        for (int kc = 0; kc < 2; kc++)
#pragma unroll
            for (int i = 0; i < 2; i++)
#pragma unroll
                for (int j = 0; j < 2; j++)
                    acc[i][j] = __builtin_amdgcn_mfma_f32_32x32x16_bf16(af[i][kc], bv[j][kc], acc[i][j], 0, 0, 0);
        __syncthreads();
    }

    // C/D layout: col=lane&31, row=(reg&3)+8*(reg>>2)+4*(lane>>5)
    if (n0 < 2048) {
        bool isQ = (n0 < 1024);
        bf16* dst = isQ ? qb : kb;
        float scale = isQ ? QSCALE : 1.0f;
        int obase = n0 & 1023;
#pragma unroll
        for (int i = 0; i < 2; i++)
#pragma unroll
            for (int j = 0; j < 2; j++) {
                int o = obase + wn + j * 32 + e31;
                int h = o >> 6, d = o & 63;
#pragma unroll
                for (int r = 0; r < 16; r++) {
                    int trow = m0 + wm + i * 32 + (r & 3) + 8 * (r >> 2) + 4 * h2;
                    dst[((size_t)(h * T_SEQ + trow)) * 64 + d] = (bf16)(acc[i][j][r] * scale);
                }
            }
    } else {
        int obase = n0 - 2048;
#pragma unroll
        for (int i = 0; i < 2; i++)
#pragma unroll
            for (int j = 0; j < 2; j++) {
                int o = obase + wn + j * 32 + e31;       // h*64+d
                size_t base = (size_t)o * T_SEQ;
#pragma unroll
                for (int rq = 0; rq < 4; rq++) {
                    int tbase = m0 + wm + i * 32 + 8 * rq + 4 * h2;
                    bf16x4 pk;
#pragma unroll
                    for (int rr = 0; rr < 4; rr++) pk[rr] = (bf16)acc[i][j][rq * 4 + rr];
                    *(bf16x4*)(vtb + base + tbase) = pk;
                }
            }
    }
}

// ---------------------------------------------------------------------------
// Banded attention: block = (head, 128 q-rows), 4 waves, wave owns 32 rows;
// key window [rowbase-128, rowbase+32) = 10 x 16 tiles (exact band support).
// Q pre-scaled by 0.125*log2e -> softmax = plain exp2 sum, NO max-subtract
// (scores are O(1) in log2 domain; overflow needs |s|>127, impossible here).
// Prologue: Wo fp32->bf16 (512 blk x 256 thr x 8 = 1048576 exactly).
// ---------------------------------------------------------------------------
#define PSTR 168

__global__ __launch_bounds__(256) void attn(
        const bf16* __restrict__ qbuf, const bf16* __restrict__ kbuf,
        const bf16* __restrict__ vtbuf, bf16* __restrict__ yb,
        const float* __restrict__ wo, bf16* __restrict__ wob) {
    __shared__ __align__(16) bf16 p_lds[4 * 32 * PSTR];
    int t = threadIdx.x;
    int w = t >> 6, l = t & 63;
    int quad = l >> 4, col = l & 15;

    {   // Wo conversion
        size_t g = ((size_t)blockIdx.x * 256 + t) * 8;
        const float4* sv = (const float4*)(wo + g);
        float4 a = sv[0], b = sv[1];
        bf16x8 o8;
        o8[0] = (bf16)a.x; o8[1] = (bf16)a.y; o8[2] = (bf16)a.z; o8[3] = (bf16)a.w;
        o8[4] = (bf16)b.x; o8[5] = (bf16)b.y; o8[6] = (bf16)b.z; o8[7] = (bf16)b.w;
        *(bf16x8*)(wob + g) = o8;
    }

    int h = blockIdx.x >> 5;
    int qt = blockIdx.x & 31;
    int i0 = qt * 128;
    int rowbase = i0 + w * 32;
    int jbase = rowbase - 128;

    const bf16* Q  = qbuf  + (size_t)h * T_SEQ * 64;
    const bf16* Kp = kbuf  + (size_t)h * T_SEQ * 64;
    const bf16* Vt = vtbuf + (size_t)h * 64 * T_SEQ;

    bf16x8 qf[2][2];
#pragma unroll
    for (int mi = 0; mi < 2; mi++)
#pragma unroll
        for (int kk = 0; kk < 2; kk++)
            qf[mi][kk] = *(const bf16x8*)(Q + (size_t)(rowbase + mi * 16 + col) * 64 + kk * 32 + quad * 8);

    f32x4 s[2][10];
#pragma unroll
    for (int mi = 0; mi < 2; mi++)
#pragma unroll
        for (int nj = 0; nj < 10; nj++) s[mi][nj] = (f32x4){0.f, 0.f, 0.f, 0.f};
#pragma unroll
    for (int nj = 0; nj < 10; nj++) {
        int jr = jbase + nj * 16 + col;
        int jl = jr < 0 ? 0 : jr;
#pragma unroll
        for (int kk = 0; kk < 2; kk++) {
            bf16x8 kf = *(const bf16x8*)(Kp + (size_t)jl * 64 + kk * 32 + quad * 8);
#pragma unroll
            for (int mi = 0; mi < 2; mi++)
                s[mi][nj] = __builtin_amdgcn_mfma_f32_16x16x32_bf16(qf[mi][kk], kf, s[mi][nj], 0, 0, 0);
        }
    }

    // mask + exp2 + row-sum (no max-subtract)
    float l_run[2][4];
#pragma unroll
    for (int mi = 0; mi < 2; mi++)
#pragma unroll
        for (int r = 0; r < 4; r++) {
            int ii = rowbase + mi * 16 + quad * 4 + r;
            float rs = 0.f;
#pragma unroll
            for (int nj = 0; nj < 10; nj++) {
                int jj = jbase + nj * 16 + col;
                bool ok = (jj >= 0) && ((unsigned)(ii - jj) < (unsigned)BAND);
                float p = ok ? __builtin_amdgcn_exp2f(s[mi][nj][r]) : 0.f;
                s[mi][nj][r] = p;
                rs += p;
            }
            rs += __shfl_xor(rs, 1);
            rs += __shfl_xor(rs, 2);
            rs += __shfl_xor(rs, 4);
            rs += __shfl_xor(rs, 8);
            l_run[mi][r] = rs;
        }

    bf16* myp = p_lds + (size_t)w * (32 * PSTR);
#pragma unroll
    for (int mi = 0; mi < 2; mi++)
#pragma unroll
        for (int nj = 0; nj < 10; nj++)
#pragma unroll
            for (int r = 0; r < 4; r++)
                myp[(mi * 16 + quad * 4 + r) * PSTR + nj * 16 + col] = (bf16)s[mi][nj][r];

    f32x4 o_acc[2][4];
#pragma unroll
    for (int mi = 0; mi < 2; mi++)
#pragma unroll
        for (int di = 0; di < 4; di++) o_acc[mi][di] = (f32x4){0.f, 0.f, 0.f, 0.f};
#pragma unroll
    for (int kj = 0; kj < 5; kj++) {
        int jv = jbase + kj * 32 + quad * 8;
        int jvc = jv < 0 ? 0 : jv;
        bf16x8 pf[2];
#pragma unroll
        for (int mi = 0; mi < 2; mi++)
            pf[mi] = *(const bf16x8*)(myp + (mi * 16 + col) * PSTR + kj * 32 + quad * 8);
#pragma unroll
        for (int di = 0; di < 4; di++) {
            bf16x8 vf = *(const bf16x8*)(Vt + (size_t)(di * 16 + col) * T_SEQ + jvc);
#pragma unroll
            for (int mi = 0; mi < 2; mi++)
                o_acc[mi][di] = __builtin_amdgcn_mfma_f32_16x16x32_bf16(pf[mi], vf, o_acc[mi][di], 0, 0, 0);
        }
    }

#pragma unroll
    for (int mi = 0; mi < 2; mi++)
#pragma unroll
        for (int di = 0; di < 4; di++)
#pragma unroll
            for (int r = 0; r < 4; r++) {
                int tt = rowbase + mi * 16 + quad * 4 + r;
                int c = h * 64 + di * 16 + col;
                yb[(size_t)tt * CDIM + c] = (bf16)(o_acc[mi][di][r] / l_run[mi][r]);
            }
}

// ---------------------------------------------------------------------------
// Output projection: out[t,o] = sum_c y[t,c]*Wo[o,c], fp32 out.
// 64x128 tile -> 512 blocks; 4 waves as 2x2 of (32m x 64n); 32x32x16 MFMA.
// ---------------------------------------------------------------------------
__global__ __launch_bounds__(256) void gemm_proj(
        const bf16* __restrict__ A, const bf16* __restrict__ B,
        float* __restrict__ Cout) {
    const int K = 1024;
    __shared__ __align__(16) bf16 lds_a[64 * 32];
    __shared__ __align__(16) bf16 lds_b[128 * 32];
    int t = threadIdx.x;
    int w = t >> 6, l = t & 63;
    int e31 = l & 31, h2 = l >> 5;
    int bx = blockIdx.x;
    int bm = bx & 63, bn = bx >> 6;          // 64 x 8 blocks
    int m0 = bm * 64, n0 = bn * 128;
    int wm = (w >> 1) * 32, wn = (w & 1) * 64;

    f32x16 acc[2];
#pragma unroll
    for (int j = 0; j < 2; j++)
#pragma unroll
        for (int r = 0; r < 16; r++) acc[j][r] = 0.f;

    int c0 = t, c1 = 256 + t;
    int ra0 = c0 >> 2, ra1 = c1 >> 2;
    int ka0 = ((c0 & 3) ^ SWZ(ra0)) * 8;
    int ka1 = ((c1 & 3) ^ SWZ(ra1)) * 8;
    bf16* la0 = lds_a + w * 512;
    bf16* lb0 = lds_b + w * 512;
    bf16* lb1 = lds_b + 2048 + w * 512;

    const bf16x8* pa[2];
    const bf16x8* pb[2][2];
    {
        int rowa = wm + e31;
        int sa = SWZ(rowa);
#pragma unroll
        for (int kc = 0; kc < 2; kc++)
            pa[kc] = (const bf16x8*)(lds_a + rowa * 32 + ((kc * 2 + h2) ^ sa) * 8);
#pragma unroll
        for (int j = 0; j < 2; j++) {
            int rowb = wn + j * 32 + e31;
            int sb = SWZ(rowb);
#pragma unroll
            for (int kc = 0; kc < 2; kc++)
                pb[j][kc] = (const bf16x8*)(lds_b + rowb * 32 + ((kc * 2 + h2) ^ sb) * 8);
        }
    }

    for (int k0 = 0; k0 < K; k0 += 32) {
        async_ld16(A + (size_t)(m0 + ra0) * K + k0 + ka0, la0);
        async_ld16(B + (size_t)(n0 + ra0) * K + k0 + ka0, lb0);
        async_ld16(B + (size_t)(n0 + ra1) * K + k0 + ka1, lb1);
        __syncthreads();
        bf16x8 af[2], bv[2][2];
#pragma unroll
        for (int kc = 0; kc < 2; kc++) {
            af[kc] = *pa[kc];
#pragma unroll
            for (int j = 0; j < 2; j++) bv[j][kc] = *pb[j][kc];
        }
#pragma unroll
        for (int kc = 0; kc < 2; kc++)
#pragma unroll
            for (int j = 0; j < 2; j++)
                acc[j] = __builtin_amdgcn_mfma_f32_32x32x16_bf16(af[kc], bv[j][kc], acc[j], 0, 0, 0);
        __syncthreads();
    }
#pragma unroll
    for (int j = 0; j < 2; j++) {
        int ncol = n0 + wn + j * 32 + e31;
#pragma unroll
        for (int r = 0; r < 16; r++) {
            int trow = m0 + wm + (r & 3) + 8 * (r >> 2) + 4 * h2;
            Cout[(size_t)trow * CDIM + ncol] = acc[j][r];
        }
    }
}

extern "C" void kernel_launch(void* const* d_in, const int* in_sizes, int n_in,
                              void* d_out, int out_size, void* d_ws, size_t ws_size,
                              hipStream_t stream) {
    const float* x  = (const float*)d_in[0];
    const float* Wq = (const float*)d_in[1];
    const float* Wk = (const float*)d_in[2];
    const float* Wv = (const float*)d_in[3];
    const float* Wo = (const float*)d_in[4];
    float* out = (float*)d_out;

    char* ws = (char*)d_ws;
    bf16* xb    = (bf16*)(ws);                        //  8 MB  x bf16
    bf16* wqkvb = (bf16*)(ws + ((size_t)8  << 20));   //  6 MB  [Wq;Wk;Wv]
    bf16* wob   = (bf16*)(ws + ((size_t)14 << 20));   //  2 MB  Wo
    bf16* qb    = (bf16*)(ws + ((size_t)16 << 20));   //  8 MB  Q (H,T,64), pre-scaled
    bf16* kb    = (bf16*)(ws + ((size_t)24 << 20));   //  8 MB  K (H,T,64)
    bf16* vtb   = (bf16*)(ws + ((size_t)32 << 20));   //  8 MB  V^T (H*64,T)
    bf16* yb    = (bf16*)(ws + ((size_t)40 << 20));   //  8 MB  y (T,C)

    cvt_all<<<3584, 256, 0, stream>>>(x, Wq, Wk, Wv, xb, wqkvb);
    gemm_qkv<<<768, 256, 0, stream>>>(xb, wqkvb, qb, kb, vtb);
    attn<<<512, 256, 0, stream>>>(qb, kb, vtb, yb, Wo, wob);
    gemm_proj<<<512, 256, 0, stream>>>(yb, wob, out);
}

// Round 5
// 144.561 us; speedup vs baseline: 1.1265x; 1.0270x over previous
//
#include <hip/hip_runtime.h>
#include <hip/hip_bf16.h>
#include <stdint.h>

#define T_SEQ 4096
#define CDIM  1024
#define NH    16
#define DHEAD 64
#define BAND  128

typedef __bf16 bf16;
typedef __attribute__((ext_vector_type(8)))  __bf16 bf16x8;
typedef __attribute__((ext_vector_type(4)))  __bf16 bf16x4;
typedef __attribute__((ext_vector_type(4)))  float  f32x4;
typedef __attribute__((ext_vector_type(16))) float  f32x16;

// 0.125 (1/sqrt(64)) * log2(e): folded into Q so attn softmax is pure exp2
#define QSCALE 0.1803368801111204f

__device__ __forceinline__ void async_ld16(const bf16* g, bf16* l) {
    __builtin_amdgcn_global_load_lds(
        (__attribute__((address_space(1))) void*)g,
        (__attribute__((address_space(3))) void*)l, 16, 0, 0);
}

// ---------------------------------------------------------------------------
// fp32 -> bf16, 8 elems/thread: x (4194304) + [Wq;Wk;Wv] (3145728)
// ---------------------------------------------------------------------------
__global__ void cvt_all(const float* __restrict__ x,  const float* __restrict__ wq,
                        const float* __restrict__ wk, const float* __restrict__ wv,
                        bf16* __restrict__ xb, bf16* __restrict__ wqkvb) {
    size_t g = (size_t)blockIdx.x * 256 + threadIdx.x;
    const float* s; bf16* d;
    if (g < 524288) {
        s = x + g * 8; d = xb + g * 8;
    } else {
        size_t i2 = (g - 524288) * 8;
        int which = (int)(i2 >> 20);
        s = ((which == 0) ? wq : (which == 1) ? wk : wv) + (i2 & 1048575);
        d = wqkvb + i2;
    }
    const float4* sv = (const float4*)s;
    float4 a = sv[0], b = sv[1];
    bf16x8 o;
    o[0] = (bf16)a.x; o[1] = (bf16)a.y; o[2] = (bf16)a.z; o[3] = (bf16)a.w;
    o[4] = (bf16)b.x; o[5] = (bf16)b.y; o[6] = (bf16)b.z; o[7] = (bf16)b.w;
    *(bf16x8*)d = o;
}

// ---------------------------------------------------------------------------
// QKV GEMM: C[m,n] = sum_k A[m,k]*B[n,k]   A=4096x1024 (x), B=3072x1024
// 128x128 tile, BK=64 (16 iters, half the barrier drains), 4 waves (2x2 of
// 64x64), 32x32x16 bf16 MFMA. LDS rows of 64 elems with 8-slot XOR swizzle
// (phys = logical ^ (row&7)) -> conflict-free b128 frag reads.
//   Q (n<1024):  (H,T,64) scaled by QSCALE   K (n<2048): (H,T,64)
//   V (n>=2048): V^T (H*64,T) via packed bf16x4 register-quad stores
// ---------------------------------------------------------------------------
__global__ __launch_bounds__(256) void gemm_qkv(
        const bf16* __restrict__ A, const bf16* __restrict__ B,
        bf16* __restrict__ qb, bf16* __restrict__ kb, bf16* __restrict__ vtb) {
    const int K = 1024;
    __shared__ __align__(16) bf16 lds_a[128 * 64];   // 16 KB
    __shared__ __align__(16) bf16 lds_b[128 * 64];   // 16 KB
    int t = threadIdx.x;
    int w = t >> 6, l = t & 63;
    int e31 = l & 31, h2 = l >> 5;
    int bx = blockIdx.x;
    int bm = bx & 31, bn = bx >> 5;          // 32 x 24 blocks
    int m0 = bm * 128, n0 = bn * 128;
    int wm = (w >> 1) * 64, wn = (w & 1) * 64;

    f32x16 acc[2][2];
#pragma unroll
    for (int i = 0; i < 2; i++)
#pragma unroll
        for (int j = 0; j < 2; j++)
#pragma unroll
            for (int r = 0; r < 16; r++) acc[i][j][r] = 0.f;

    // staging: chunk cid = it*256+t -> row=cid>>3, phys slot=cid&7,
    // fetch logical chunk (cid&7)^(row&7); LDS dest = cid*8 elems (contig)
    int row_s[4], ko_s[4];
#pragma unroll
    for (int it = 0; it < 4; it++) {
        int cid = it * 256 + t;
        row_s[it] = cid >> 3;
        ko_s[it] = ((cid & 7) ^ (row_s[it] & 7)) * 8;
    }
    // frag rows + swizzle keys
    int rowa0 = wm + e31, rowa1 = wm + 32 + e31;
    int rowb0 = wn + e31, rowb1 = wn + 32 + e31;
    int sa0 = rowa0 & 7, sa1 = rowa1 & 7, sb0 = rowb0 & 7, sb1 = rowb1 & 7;
    const bf16* ba0 = lds_a + rowa0 * 64;
    const bf16* ba1 = lds_a + rowa1 * 64;
    const bf16* bb0 = lds_b + rowb0 * 64;
    const bf16* bb1 = lds_b + rowb1 * 64;

    for (int k0 = 0; k0 < K; k0 += 64) {
#pragma unroll
        for (int it = 0; it < 4; it++) {
            bf16* dst_a = lds_a + (it * 256 + w * 64) * 8;
            bf16* dst_b = lds_b + (it * 256 + w * 64) * 8;
            async_ld16(A + (size_t)(m0 + row_s[it]) * K + k0 + ko_s[it], dst_a);
            async_ld16(B + (size_t)(n0 + row_s[it]) * K + k0 + ko_s[it], dst_b);
        }
        __syncthreads();
#pragma unroll
        for (int kk = 0; kk < 4; kk++) {
            int lc = kk * 2 + h2;
            bf16x8 a0 = *(const bf16x8*)(ba0 + ((lc ^ sa0) * 8));
            bf16x8 a1 = *(const bf16x8*)(ba1 + ((lc ^ sa1) * 8));
            bf16x8 b0 = *(const bf16x8*)(bb0 + ((lc ^ sb0) * 8));
            bf16x8 b1 = *(const bf16x8*)(bb1 + ((lc ^ sb1) * 8));
            acc[0][0] = __builtin_amdgcn_mfma_f32_32x32x16_bf16(a0, b0, acc[0][0], 0, 0, 0);
            acc[0][1] = __builtin_amdgcn_mfma_f32_32x32x16_bf16(a0, b1, acc[0][1], 0, 0, 0);
            acc[1][0] = __builtin_amdgcn_mfma_f32_32x32x16_bf16(a1, b0, acc[1][0], 0, 0, 0);
            acc[1][1] = __builtin_amdgcn_mfma_f32_32x32x16_bf16(a1, b1, acc[1][1], 0, 0, 0);
        }
        __syncthreads();
    }

    // C/D layout: col=lane&31, row=(reg&3)+8*(reg>>2)+4*(lane>>5)
    if (n0 < 2048) {
        bool isQ = (n0 < 1024);
        bf16* dst = isQ ? qb : kb;
        float scale = isQ ? QSCALE : 1.0f;
        int obase = n0 & 1023;
#pragma unroll
        for (int i = 0; i < 2; i++)
#pragma unroll
            for (int j = 0; j < 2; j++) {
                int o = obase + wn + j * 32 + e31;
                int h = o >> 6, d = o & 63;
#pragma unroll
                for (int r = 0; r < 16; r++) {
                    int trow = m0 + wm + i * 32 + (r & 3) + 8 * (r >> 2) + 4 * h2;
                    dst[((size_t)(h * T_SEQ + trow)) * 64 + d] = (bf16)(acc[i][j][r] * scale);
                }
            }
    } else {
        int obase = n0 - 2048;
#pragma unroll
        for (int i = 0; i < 2; i++)
#pragma unroll
            for (int j = 0; j < 2; j++) {
                int o = obase + wn + j * 32 + e31;       // h*64+d
                size_t base = (size_t)o * T_SEQ;
#pragma unroll
                for (int rq = 0; rq < 4; rq++) {
                    int tbase = m0 + wm + i * 32 + 8 * rq + 4 * h2;
                    bf16x4 pk;
#pragma unroll
                    for (int rr = 0; rr < 4; rr++) pk[rr] = (bf16)acc[i][j][rq * 4 + rr];
                    *(bf16x4*)(vtb + base + tbase) = pk;
                }
            }
    }
}

// ---------------------------------------------------------------------------
// Banded attention: block = (head, 128 q-rows), 4 waves, wave owns 32 rows;
// key window [rowbase-128, rowbase+32) = 10 x 16 tiles (exact band support).
// Q pre-scaled by 0.125*log2e -> softmax = plain exp2 sum, no max-subtract.
// Prologue: Wo fp32->bf16 (512 blk x 256 thr x 8 = 1048576 exactly).
// ---------------------------------------------------------------------------
#define PSTR 168

__global__ __launch_bounds__(256) void attn(
        const bf16* __restrict__ qbuf, const bf16* __restrict__ kbuf,
        const bf16* __restrict__ vtbuf, bf16* __restrict__ yb,
        const float* __restrict__ wo, bf16* __restrict__ wob) {
    __shared__ __align__(16) bf16 p_lds[4 * 32 * PSTR];
    int t = threadIdx.x;
    int w = t >> 6, l = t & 63;
    int quad = l >> 4, col = l & 15;

    {   // Wo conversion
        size_t g = ((size_t)blockIdx.x * 256 + t) * 8;
        const float4* sv = (const float4*)(wo + g);
        float4 a = sv[0], b = sv[1];
        bf16x8 o8;
        o8[0] = (bf16)a.x; o8[1] = (bf16)a.y; o8[2] = (bf16)a.z; o8[3] = (bf16)a.w;
        o8[4] = (bf16)b.x; o8[5] = (bf16)b.y; o8[6] = (bf16)b.z; o8[7] = (bf16)b.w;
        *(bf16x8*)(wob + g) = o8;
    }

    int h = blockIdx.x >> 5;
    int qt = blockIdx.x & 31;
    int i0 = qt * 128;
    int rowbase = i0 + w * 32;
    int jbase = rowbase - 128;

    const bf16* Q  = qbuf  + (size_t)h * T_SEQ * 64;
    const bf16* Kp = kbuf  + (size_t)h * T_SEQ * 64;
    const bf16* Vt = vtbuf + (size_t)h * 64 * T_SEQ;

    bf16x8 qf[2][2];
#pragma unroll
    for (int mi = 0; mi < 2; mi++)
#pragma unroll
        for (int kk = 0; kk < 2; kk++)
            qf[mi][kk] = *(const bf16x8*)(Q + (size_t)(rowbase + mi * 16 + col) * 64 + kk * 32 + quad * 8);

    f32x4 s[2][10];
#pragma unroll
    for (int mi = 0; mi < 2; mi++)
#pragma unroll
        for (int nj = 0; nj < 10; nj++) s[mi][nj] = (f32x4){0.f, 0.f, 0.f, 0.f};
#pragma unroll
    for (int nj = 0; nj < 10; nj++) {
        int jr = jbase + nj * 16 + col;
        int jl = jr < 0 ? 0 : jr;
#pragma unroll
        for (int kk = 0; kk < 2; kk++) {
            bf16x8 kf = *(const bf16x8*)(Kp + (size_t)jl * 64 + kk * 32 + quad * 8);
#pragma unroll
            for (int mi = 0; mi < 2; mi++)
                s[mi][nj] = __builtin_amdgcn_mfma_f32_16x16x32_bf16(qf[mi][kk], kf, s[mi][nj], 0, 0, 0);
        }
    }

    // mask + exp2 + row-sum (no max-subtract)
    float l_run[2][4];
#pragma unroll
    for (int mi = 0; mi < 2; mi++)
#pragma unroll
        for (int r = 0; r < 4; r++) {
            int ii = rowbase + mi * 16 + quad * 4 + r;
            float rs = 0.f;
#pragma unroll
            for (int nj = 0; nj < 10; nj++) {
                int jj = jbase + nj * 16 + col;
                bool ok = (jj >= 0) && ((unsigned)(ii - jj) < (unsigned)BAND);
                float p = ok ? __builtin_amdgcn_exp2f(s[mi][nj][r]) : 0.f;
                s[mi][nj][r] = p;
                rs += p;
            }
            rs += __shfl_xor(rs, 1);
            rs += __shfl_xor(rs, 2);
            rs += __shfl_xor(rs, 4);
            rs += __shfl_xor(rs, 8);
            l_run[mi][r] = rs;
        }

    bf16* myp = p_lds + (size_t)w * (32 * PSTR);
#pragma unroll
    for (int mi = 0; mi < 2; mi++)
#pragma unroll
        for (int nj = 0; nj < 10; nj++)
#pragma unroll
            for (int r = 0; r < 4; r++)
                myp[(mi * 16 + quad * 4 + r) * PSTR + nj * 16 + col] = (bf16)s[mi][nj][r];

    f32x4 o_acc[2][4];
#pragma unroll
    for (int mi = 0; mi < 2; mi++)
#pragma unroll
        for (int di = 0; di < 4; di++) o_acc[mi][di] = (f32x4){0.f, 0.f, 0.f, 0.f};
#pragma unroll
    for (int kj = 0; kj < 5; kj++) {
        int jv = jbase + kj * 32 + quad * 8;
        int jvc = jv < 0 ? 0 : jv;
        bf16x8 pf[2];
#pragma unroll
        for (int mi = 0; mi < 2; mi++)
            pf[mi] = *(const bf16x8*)(myp + (mi * 16 + col) * PSTR + kj * 32 + quad * 8);
#pragma unroll
        for (int di = 0; di < 4; di++) {
            bf16x8 vf = *(const bf16x8*)(Vt + (size_t)(di * 16 + col) * T_SEQ + jvc);
#pragma unroll
            for (int mi = 0; mi < 2; mi++)
                o_acc[mi][di] = __builtin_amdgcn_mfma_f32_16x16x32_bf16(pf[mi], vf, o_acc[mi][di], 0, 0, 0);
        }
    }

#pragma unroll
    for (int mi = 0; mi < 2; mi++)
#pragma unroll
        for (int di = 0; di < 4; di++)
#pragma unroll
            for (int r = 0; r < 4; r++) {
                int tt = rowbase + mi * 16 + quad * 4 + r;
                int c = h * 64 + di * 16 + col;
                yb[(size_t)tt * CDIM + c] = (bf16)(o_acc[mi][di][r] / l_run[mi][r]);
            }
}

// ---------------------------------------------------------------------------
// Output projection: out[t,o] = sum_c y[t,c]*Wo[o,c], fp32 out.
// 64x128 tile, BK=64 -> 512 blocks; 4 waves as 2x2 of (32m x 64n); 32x32x16.
// ---------------------------------------------------------------------------
__global__ __launch_bounds__(256) void gemm_proj(
        const bf16* __restrict__ A, const bf16* __restrict__ B,
        float* __restrict__ Cout) {
    const int K = 1024;
    __shared__ __align__(16) bf16 lds_a[64 * 64];    //  8 KB
    __shared__ __align__(16) bf16 lds_b[128 * 64];   // 16 KB
    int t = threadIdx.x;
    int w = t >> 6, l = t & 63;
    int e31 = l & 31, h2 = l >> 5;
    int bx = blockIdx.x;
    int bm = bx & 63, bn = bx >> 6;          // 64 x 8 blocks
    int m0 = bm * 64, n0 = bn * 128;
    int wm = (w >> 1) * 32, wn = (w & 1) * 64;

    f32x16 acc[2];
#pragma unroll
    for (int j = 0; j < 2; j++)
#pragma unroll
        for (int r = 0; r < 16; r++) acc[j][r] = 0.f;

    int rowA[2], koA[2], rowB[4], koB[4];
#pragma unroll
    for (int it = 0; it < 2; it++) {
        int cid = it * 256 + t;
        rowA[it] = cid >> 3;
        koA[it] = ((cid & 7) ^ (rowA[it] & 7)) * 8;
    }
#pragma unroll
    for (int it = 0; it < 4; it++) {
        int cid = it * 256 + t;
        rowB[it] = cid >> 3;
        koB[it] = ((cid & 7) ^ (rowB[it] & 7)) * 8;
    }
    int rowa = wm + e31;
    int rowb0 = wn + e31, rowb1 = wn + 32 + e31;
    int sa = rowa & 7, sb0 = rowb0 & 7, sb1 = rowb1 & 7;
    const bf16* ba = lds_a + rowa * 64;
    const bf16* bb0 = lds_b + rowb0 * 64;
    const bf16* bb1 = lds_b + rowb1 * 64;

    for (int k0 = 0; k0 < K; k0 += 64) {
#pragma unroll
        for (int it = 0; it < 2; it++)
            async_ld16(A + (size_t)(m0 + rowA[it]) * K + k0 + koA[it],
                       lds_a + (it * 256 + w * 64) * 8);
#pragma unroll
        for (int it = 0; it < 4; it++)
            async_ld16(B + (size_t)(n0 + rowB[it]) * K + k0 + koB[it],
                       lds_b + (it * 256 + w * 64) * 8);
        __syncthreads();
#pragma unroll
        for (int kk = 0; kk < 4; kk++) {
            int lc = kk * 2 + h2;
            bf16x8 af = *(const bf16x8*)(ba + ((lc ^ sa) * 8));
            bf16x8 b0 = *(const bf16x8*)(bb0 + ((lc ^ sb0) * 8));
            bf16x8 b1 = *(const bf16x8*)(bb1 + ((lc ^ sb1) * 8));
            acc[0] = __builtin_amdgcn_mfma_f32_32x32x16_bf16(af, b0, acc[0], 0, 0, 0);
            acc[1] = __builtin_amdgcn_mfma_f32_32x32x16_bf16(af, b1, acc[1], 0, 0, 0);
        }
        __syncthreads();
    }
#pragma unroll
    for (int j = 0; j < 2; j++) {
        int ncol = n0 + wn + j * 32 + e31;
#pragma unroll
        for (int r = 0; r < 16; r++) {
            int trow = m0 + wm + (r & 3) + 8 * (r >> 2) + 4 * h2;
            Cout[(size_t)trow * CDIM + ncol] = acc[j][r];
        }
    }
}

extern "C" void kernel_launch(void* const* d_in, const int* in_sizes, int n_in,
                              void* d_out, int out_size, void* d_ws, size_t ws_size,
                              hipStream_t stream) {
    const float* x  = (const float*)d_in[0];
    const float* Wq = (const float*)d_in[1];
    const float* Wk = (const float*)d_in[2];
    const float* Wv = (const float*)d_in[3];
    const float* Wo = (const float*)d_in[4];
    float* out = (float*)d_out;

    char* ws = (char*)d_ws;
    bf16* xb    = (bf16*)(ws);                        //  8 MB  x bf16
    bf16* wqkvb = (bf16*)(ws + ((size_t)8  << 20));   //  6 MB  [Wq;Wk;Wv]
    bf16* wob   = (bf16*)(ws + ((size_t)14 << 20));   //  2 MB  Wo
    bf16* qb    = (bf16*)(ws + ((size_t)16 << 20));   //  8 MB  Q (H,T,64), pre-scaled
    bf16* kb    = (bf16*)(ws + ((size_t)24 << 20));   //  8 MB  K (H,T,64)
    bf16* vtb   = (bf16*)(ws + ((size_t)32 << 20));   //  8 MB  V^T (H*64,T)
    bf16* yb    = (bf16*)(ws + ((size_t)40 << 20));   //  8 MB  y (T,C)

    cvt_all<<<3584, 256, 0, stream>>>(x, Wq, Wk, Wv, xb, wqkvb);
    gemm_qkv<<<768, 256, 0, stream>>>(xb, wqkvb, qb, kb, vtb);
    attn<<<512, 256, 0, stream>>>(qb, kb, vtb, yb, Wo, wob);
    gemm_proj<<<512, 256, 0, stream>>>(yb, wob, out);
}